// Round 15
// baseline (214.927 us; speedup 1.0000x reference)
//
#include <hip/hip_runtime.h>

#define N_NODES 100000
#define N_FEATS 256
#define OUT_DIM 64
#define NNZ_X   1280000
#define N_EDGES 1600000
#define NB      391     // ceil(N_NODES/256); bucket = row >> 8
#define CHUNK   2048    // entries per phase-1 block (512 thr, 4/thread)
#define KPT     4
#define CAPX    4352    // X slab capacity (kept-mean 2949, sigma ~54: +25 sigma)
#define CAPA    5120    // A slab capacity (mean 4092, sigma ~64: +16 sigma)

// ---------------- JAX threefry2x32 (partitionable mode, verified R2) ----------------
__device__ __forceinline__ unsigned rotl32(unsigned x, unsigned d) {
    return (x << d) | (x >> (32u - d));
}

__device__ __forceinline__ float jax_uniform_42(unsigned e) {
    unsigned x0 = 0u, x1 = e;
    const unsigned ks0 = 0u, ks1 = 42u, ks2 = 0u ^ 42u ^ 0x1BD11BDAu;
    x0 += ks0; x1 += ks1;
#define TF_R(r) { x0 += x1; x1 = rotl32(x1, r); x1 ^= x0; }
    TF_R(13) TF_R(15) TF_R(26) TF_R(6)
    x0 += ks1; x1 += ks2 + 1u;
    TF_R(17) TF_R(29) TF_R(16) TF_R(24)
    x0 += ks2; x1 += ks0 + 2u;
    TF_R(13) TF_R(15) TF_R(26) TF_R(6)
    x0 += ks0; x1 += ks1 + 3u;
    TF_R(17) TF_R(29) TF_R(16) TF_R(24)
    x0 += ks1; x1 += ks2 + 4u;
    TF_R(13) TF_R(15) TF_R(26) TF_R(6)
    x0 += ks2; x1 += ks0 + 5u;
#undef TF_R
    unsigned bits = x0 ^ x1;
    return __uint_as_float((bits >> 9) | 0x3f800000u) - 1.0f;
}

__device__ __forceinline__ bool keep_42(unsigned e) {
    float u = jax_uniform_42(e);
    return floorf(0.9f + u) != 0.0f;
}

// f32 -> bf16 round-to-nearest-even
__device__ __forceinline__ unsigned short f32_bf16(float f) {
    unsigned bits = __float_as_uint(f);
    return (unsigned short)((bits + 0x7fffu + ((bits >> 16) & 1u)) >> 16);
}

__device__ __forceinline__ float bf16_f32(unsigned short u) {
    return __uint_as_float((unsigned)u << 16);
}

// ---------------- phase 1: LDS-binned grouping, CHUNK 2048, shuffle scan -------
__global__ __launch_bounds__(512) void phase1(
        const float* __restrict__ fvals, const int* __restrict__ frows,
        const int* __restrict__ fcols,
        const float* __restrict__ avals, const int* __restrict__ arows,
        const int* __restrict__ acols,
        int* __restrict__ bcur_x, int* __restrict__ bcur_a,
        float2* __restrict__ gx, float2* __restrict__ ga) {
    const int isA = blockIdx.y;
    const float* vals = isA ? avals : fvals;
    const int* rows   = isA ? arows : frows;
    const int* cols   = isA ? acols : fcols;
    int* bcur         = isA ? bcur_a : bcur_x;
    float2* dst       = isA ? ga : gx;
    const unsigned cap = isA ? CAPA : CAPX;
    const unsigned n  = isA ? N_EDGES : NNZ_X;

    unsigned t = threadIdx.x;
    unsigned wid = t >> 6, lane = t & 63u;
    unsigned base = blockIdx.x * CHUNK;
    if (base >= n) return;   // X side has fewer chunks

    __shared__ int cnt[512];
    __shared__ int start[512];
    __shared__ int cur[512];
    __shared__ int gbase[NB];
    __shared__ int wtot[8];
    __shared__ unsigned pArr[CHUNK];   // (b<<20)|(rowlow<<12)|ilocal  (8 KB)

    int rcache[KPT];

    cnt[t] = 0;
    __syncthreads();
    // pass 1: read rows once, hist kept entries per bucket
    #pragma unroll
    for (int k = 0; k < KPT; k++) {
        unsigned i = base + k * 512u + t;
        int r = -1;
        if (i < n) {
            int rr = rows[i];
            if (isA || keep_42(i)) r = rr;
        }
        rcache[k] = r;
        if (r >= 0) atomicAdd(&cnt[(unsigned)r >> 8], 1);
    }
    __syncthreads();
    // shuffle scan over 512 bins: thread t owns bin t (8 waves x 64 bins)
    int binv = cnt[t];
    int inc = binv;
    #pragma unroll
    for (int d = 1; d < 64; d <<= 1) {
        int v = __shfl_up(inc, d, 64);
        if (lane >= (unsigned)d) inc += v;
    }
    if (lane == 63u) wtot[wid] = inc;
    __syncthreads();
    int offw = 0, total = 0;
    #pragma unroll
    for (int w = 0; w < 8; w++) {
        int wv = wtot[w];
        if ((unsigned)w < wid) offw += wv;
        total += wv;
    }
    int excl = inc - binv + offw;
    start[t] = excl;
    cur[t]   = excl;
    if (t < NB && binv > 0) gbase[t] = atomicAdd(&bcur[t], binv);
    __syncthreads();
    int n_valid = total;
    // pass 2: bucket-grouped permutation from register cache
    #pragma unroll
    for (int k = 0; k < KPT; k++) {
        int r = rcache[k];
        if (r >= 0) {
            unsigned b = (unsigned)r >> 8;
            int p = atomicAdd(&cur[b], 1);
            pArr[p] = (b << 20) | (((unsigned)r & 255u) << 12) | (k * 512u + t);
        }
    }
    __syncthreads();
    // pass 3: coalesced slab writes; gather cols/vals from the 8KB window
    #pragma unroll
    for (int k = 0; k < KPT; k++) {
        int sidx = k * 512 + (int)t;
        if (sidx < n_valid) {
            unsigned m = pArr[sidx];
            unsigned b = m >> 20;
            unsigned rowlow = (m >> 12) & 255u;
            unsigned i = base + (m & 2047u);
            float v = vals[i];
            if (!isA) v *= (float)(1.0 / 0.9);
            unsigned packed = ((unsigned)cols[i] << 8) | rowlow;
            float2 e; e.x = v; e.y = __int_as_float((int)packed);
            dst[(size_t)b * cap + gbase[b] + (sidx - start[b])] = e;
        }
    }
}

// ---------------- sort stage (R14 verbatim): grid 2*NB, LDS = CAPX only -------
__global__ __launch_bounds__(512) void sort_stage(
        const int* __restrict__ bcur_x, const float2* __restrict__ gx,
        const float* __restrict__ W, unsigned short* __restrict__ xw,
        const int* __restrict__ bcur_a, float2* __restrict__ ga,
        unsigned short* __restrict__ rs) {
    __shared__ float2 ent[CAPX];       // 34.8 KB
    __shared__ int hist[256];
    __shared__ int starts[256];
    __shared__ int cursor[256];
    __shared__ int wtot[4];
    unsigned t = threadIdx.x;
    unsigned wid = t >> 6, lane = t & 63u;
    const int isA = (blockIdx.x >= NB);
    unsigned b = isA ? (blockIdx.x - NB) : blockIdx.x;

    if (!isA) {
        // ================= X path =================
        int cnt = bcur_x[b];
        const float2* src = gx + (size_t)b * CAPX;
        if (t < 256) hist[t] = 0;
        __syncthreads();
        for (int i = (int)t; i < cnt; i += 512)
            atomicAdd(&hist[((unsigned)__float_as_int(src[i].y)) & 255u], 1);
        __syncthreads();
        int inc = 0, binv = 0;
        if (wid < 4u) {
            unsigned bin = wid * 64u + lane;
            binv = hist[bin];
            inc = binv;
            #pragma unroll
            for (int d = 1; d < 64; d <<= 1) {
                int v = __shfl_up(inc, d, 64);
                if (lane >= (unsigned)d) inc += v;
            }
            if (lane == 63u) wtot[wid] = inc;
        }
        __syncthreads();
        if (wid < 4u) {
            int offw = 0;
            #pragma unroll
            for (int w = 0; w < 4; w++) if ((unsigned)w < wid) offw += wtot[w];
            unsigned bin = wid * 64u + lane;
            int excl = inc - binv + offw;
            starts[bin] = excl;
            cursor[bin] = excl;
        }
        __syncthreads();
        for (int i = (int)t; i < cnt; i += 512) {
            float2 e = src[i];
            int pos = atomicAdd(&cursor[((unsigned)__float_as_int(e.y)) & 255u], 1);
            ent[pos] = e;
        }
        __syncthreads();
        // SpMM1: 8 waves x 32 rows; quarter-wave float4 W gathers
        unsigned quarter = lane >> 4, sub = lane & 15u;
        const float4* W4 = (const float4*)W;
        ushort4* xw4 = (ushort4*)xw;
        for (unsigned r = wid; r < 256u; r += 8u) {
            int s0 = starts[r];
            int s1 = (r == 255u) ? cnt : starts[r + 1];
            float4 acc[4];
            #pragma unroll
            for (int j = 0; j < 4; j++) { acc[j].x = acc[j].y = acc[j].z = acc[j].w = 0.0f; }
            int p = s0;
            for (; p + 16 <= s1; p += 16) {
                float2 e[4];
                #pragma unroll
                for (int j = 0; j < 4; j++) e[j] = ent[p + 4 * quarter + j];
                float4 w[4];
                #pragma unroll
                for (int j = 0; j < 4; j++)
                    w[j] = W4[(((unsigned)__float_as_int(e[j].y)) >> 8) * 16u + sub];
                #pragma unroll
                for (int j = 0; j < 4; j++) {
                    acc[j].x = fmaf(e[j].x, w[j].x, acc[j].x);
                    acc[j].y = fmaf(e[j].x, w[j].y, acc[j].y);
                    acc[j].z = fmaf(e[j].x, w[j].z, acc[j].z);
                    acc[j].w = fmaf(e[j].x, w[j].w, acc[j].w);
                }
            }
            for (int q = p + (int)quarter; q < s1; q += 4) {
                float2 e = ent[q];
                float4 w = W4[(((unsigned)__float_as_int(e.y)) >> 8) * 16u + sub];
                acc[0].x = fmaf(e.x, w.x, acc[0].x);
                acc[0].y = fmaf(e.x, w.y, acc[0].y);
                acc[0].z = fmaf(e.x, w.z, acc[0].z);
                acc[0].w = fmaf(e.x, w.w, acc[0].w);
            }
            float ax = (acc[0].x + acc[1].x) + (acc[2].x + acc[3].x);
            float ay = (acc[0].y + acc[1].y) + (acc[2].y + acc[3].y);
            float az = (acc[0].z + acc[1].z) + (acc[2].z + acc[3].z);
            float aw = (acc[0].w + acc[1].w) + (acc[2].w + acc[3].w);
            ax += __shfl(ax, (int)(lane ^ 16u), 64);
            ay += __shfl(ay, (int)(lane ^ 16u), 64);
            az += __shfl(az, (int)(lane ^ 16u), 64);
            aw += __shfl(aw, (int)(lane ^ 16u), 64);
            ax += __shfl(ax, (int)(lane ^ 32u), 64);
            ay += __shfl(ay, (int)(lane ^ 32u), 64);
            az += __shfl(az, (int)(lane ^ 32u), 64);
            aw += __shfl(aw, (int)(lane ^ 32u), 64);
            unsigned grow = (b << 8) + r;
            if (quarter == 0 && grow < N_NODES) {
                ushort4 o;
                o.x = f32_bf16(ax); o.y = f32_bf16(ay);
                o.z = f32_bf16(az); o.w = f32_bf16(aw);
                xw4[(size_t)grow * 16u + sub] = o;
            }
        }
    } else {
        // ================= A path: register-staged in-place sort ==============
        int cnt = bcur_a[b];
        float2* g = ga + (size_t)b * CAPA;
        if (t < 256) hist[t] = 0;
        __syncthreads();
        float2 ec[10];
        #pragma unroll
        for (int k = 0; k < 10; k++) {
            int i = k * 512 + (int)t;
            if (i < cnt) {
                float2 e = g[i];
                ec[k] = e;
                atomicAdd(&hist[((unsigned)__float_as_int(e.y)) & 255u], 1);
            }
        }
        __syncthreads();
        int inc = 0, binv = 0;
        if (wid < 4u) {
            unsigned bin = wid * 64u + lane;
            binv = hist[bin];
            inc = binv;
            #pragma unroll
            for (int d = 1; d < 64; d <<= 1) {
                int v = __shfl_up(inc, d, 64);
                if (lane >= (unsigned)d) inc += v;
            }
            if (lane == 63u) wtot[wid] = inc;
        }
        __syncthreads();
        if (wid < 4u) {
            int offw = 0;
            #pragma unroll
            for (int w = 0; w < 4; w++) if ((unsigned)w < wid) offw += wtot[w];
            unsigned bin = wid * 64u + lane;
            int excl = inc - binv + offw;
            cursor[bin] = excl;
            rs[(b << 8) + bin] = (unsigned short)excl;
        }
        __syncthreads();
        #pragma unroll
        for (int k = 0; k < 10; k++) {
            int i = k * 512 + (int)t;
            if (i < cnt) {
                unsigned packed = (unsigned)__float_as_int(ec[k].y);
                int pos = atomicAdd(&cursor[packed & 255u], 1);
                float2 o; o.x = ec[k].x; o.y = __int_as_float((int)(packed >> 8));
                g[pos] = o;
            }
        }
    }
}

// ---------------- SpMM2 + ReLU: two rows per wave, quarter-wave ushort4 --------
// Wave handles rows (2p, 2p+1) — same bucket (row0 even). Dual-row main loop
// doubles in-flight gathers per wave.
__global__ void spmm2(const int* __restrict__ bcur_a,
                      const unsigned short* __restrict__ rs_a,
                      const float2* __restrict__ ga,
                      const unsigned short* __restrict__ xw,
                      float* __restrict__ out) {
    unsigned wid  = threadIdx.x >> 6;
    unsigned lane = threadIdx.x & 63u;
    unsigned pair = blockIdx.x * 4u + wid;
    unsigned row0 = pair * 2u;
    if (row0 >= N_NODES) return;
    unsigned row1 = row0 + 1u;
    unsigned b = row0 >> 8;
    int cnt = bcur_a[b];
    const float2* ent = ga + (size_t)b * CAPA;
    int s0a = rs_a[row0];
    int s1a = rs_a[row1];                 // row1 start == row0 end (same bucket)
    int s0b = s1a;
    unsigned rl1 = row1 & 255u;
    int s1b = (rl1 == 255u) ? cnt : (int)rs_a[row1 + 1];
    unsigned quarter = lane >> 4;
    unsigned sub     = lane & 15u;
    const ushort4* xw4 = (const ushort4*)xw;

    float4 accA[4], accB[4];
    #pragma unroll
    for (int j = 0; j < 4; j++) {
        accA[j].x = accA[j].y = accA[j].z = accA[j].w = 0.0f;
        accB[j].x = accB[j].y = accB[j].z = accB[j].w = 0.0f;
    }
    int pa = s0a, pb = s0b;
    // dual-row main loop: 8 gathers in flight per lane-slot
    while (pa + 16 <= s1a && pb + 16 <= s1b) {
        float2 ea[4], eb[4];
        #pragma unroll
        for (int j = 0; j < 4; j++) {
            ea[j] = ent[pa + 4 * quarter + j];
            eb[j] = ent[pb + 4 * quarter + j];
        }
        ushort4 ua[4], ub[4];
        #pragma unroll
        for (int j = 0; j < 4; j++) {
            ua[j] = xw4[((unsigned)__float_as_int(ea[j].y)) * 16u + sub];
            ub[j] = xw4[((unsigned)__float_as_int(eb[j].y)) * 16u + sub];
        }
        #pragma unroll
        for (int j = 0; j < 4; j++) {
            accA[j].x = fmaf(ea[j].x, bf16_f32(ua[j].x), accA[j].x);
            accA[j].y = fmaf(ea[j].x, bf16_f32(ua[j].y), accA[j].y);
            accA[j].z = fmaf(ea[j].x, bf16_f32(ua[j].z), accA[j].z);
            accA[j].w = fmaf(ea[j].x, bf16_f32(ua[j].w), accA[j].w);
            accB[j].x = fmaf(eb[j].x, bf16_f32(ub[j].x), accB[j].x);
            accB[j].y = fmaf(eb[j].x, bf16_f32(ub[j].y), accB[j].y);
            accB[j].z = fmaf(eb[j].x, bf16_f32(ub[j].z), accB[j].z);
            accB[j].w = fmaf(eb[j].x, bf16_f32(ub[j].w), accB[j].w);
        }
        pa += 16; pb += 16;
    }
    // drain row A
    for (; pa + 16 <= s1a; pa += 16) {
        float2 e[4];
        #pragma unroll
        for (int j = 0; j < 4; j++) e[j] = ent[pa + 4 * quarter + j];
        ushort4 u[4];
        #pragma unroll
        for (int j = 0; j < 4; j++)
            u[j] = xw4[((unsigned)__float_as_int(e[j].y)) * 16u + sub];
        #pragma unroll
        for (int j = 0; j < 4; j++) {
            accA[j].x = fmaf(e[j].x, bf16_f32(u[j].x), accA[j].x);
            accA[j].y = fmaf(e[j].x, bf16_f32(u[j].y), accA[j].y);
            accA[j].z = fmaf(e[j].x, bf16_f32(u[j].z), accA[j].z);
            accA[j].w = fmaf(e[j].x, bf16_f32(u[j].w), accA[j].w);
        }
    }
    for (int q = pa + (int)quarter; q < s1a; q += 4) {
        float2 e = ent[q];
        ushort4 u = xw4[((unsigned)__float_as_int(e.y)) * 16u + sub];
        accA[0].x = fmaf(e.x, bf16_f32(u.x), accA[0].x);
        accA[0].y = fmaf(e.x, bf16_f32(u.y), accA[0].y);
        accA[0].z = fmaf(e.x, bf16_f32(u.z), accA[0].z);
        accA[0].w = fmaf(e.x, bf16_f32(u.w), accA[0].w);
    }
    // drain row B
    for (; pb + 16 <= s1b; pb += 16) {
        float2 e[4];
        #pragma unroll
        for (int j = 0; j < 4; j++) e[j] = ent[pb + 4 * quarter + j];
        ushort4 u[4];
        #pragma unroll
        for (int j = 0; j < 4; j++)
            u[j] = xw4[((unsigned)__float_as_int(e[j].y)) * 16u + sub];
        #pragma unroll
        for (int j = 0; j < 4; j++) {
            accB[j].x = fmaf(e[j].x, bf16_f32(u[j].x), accB[j].x);
            accB[j].y = fmaf(e[j].x, bf16_f32(u[j].y), accB[j].y);
            accB[j].z = fmaf(e[j].x, bf16_f32(u[j].z), accB[j].z);
            accB[j].w = fmaf(e[j].x, bf16_f32(u[j].w), accB[j].w);
        }
    }
    for (int q = pb + (int)quarter; q < s1b; q += 4) {
        float2 e = ent[q];
        ushort4 u = xw4[((unsigned)__float_as_int(e.y)) * 16u + sub];
        accB[0].x = fmaf(e.x, bf16_f32(u.x), accB[0].x);
        accB[0].y = fmaf(e.x, bf16_f32(u.y), accB[0].y);
        accB[0].z = fmaf(e.x, bf16_f32(u.z), accB[0].z);
        accB[0].w = fmaf(e.x, bf16_f32(u.w), accB[0].w);
    }
    // reduce + store both rows
    float ax = (accA[0].x + accA[1].x) + (accA[2].x + accA[3].x);
    float ay = (accA[0].y + accA[1].y) + (accA[2].y + accA[3].y);
    float az = (accA[0].z + accA[1].z) + (accA[2].z + accA[3].z);
    float aw = (accA[0].w + accA[1].w) + (accA[2].w + accA[3].w);
    float bx = (accB[0].x + accB[1].x) + (accB[2].x + accB[3].x);
    float by = (accB[0].y + accB[1].y) + (accB[2].y + accB[3].y);
    float bz = (accB[0].z + accB[1].z) + (accB[2].z + accB[3].z);
    float bw = (accB[0].w + accB[1].w) + (accB[2].w + accB[3].w);
    ax += __shfl(ax, (int)(lane ^ 16u), 64);
    ay += __shfl(ay, (int)(lane ^ 16u), 64);
    az += __shfl(az, (int)(lane ^ 16u), 64);
    aw += __shfl(aw, (int)(lane ^ 16u), 64);
    bx += __shfl(bx, (int)(lane ^ 16u), 64);
    by += __shfl(by, (int)(lane ^ 16u), 64);
    bz += __shfl(bz, (int)(lane ^ 16u), 64);
    bw += __shfl(bw, (int)(lane ^ 16u), 64);
    ax += __shfl(ax, (int)(lane ^ 32u), 64);
    ay += __shfl(ay, (int)(lane ^ 32u), 64);
    az += __shfl(az, (int)(lane ^ 32u), 64);
    aw += __shfl(aw, (int)(lane ^ 32u), 64);
    bx += __shfl(bx, (int)(lane ^ 32u), 64);
    by += __shfl(by, (int)(lane ^ 32u), 64);
    bz += __shfl(bz, (int)(lane ^ 32u), 64);
    bw += __shfl(bw, (int)(lane ^ 32u), 64);
    if (quarter == 0) {
        float4 oa, ob;
        oa.x = fmaxf(ax, 0.0f); oa.y = fmaxf(ay, 0.0f);
        oa.z = fmaxf(az, 0.0f); oa.w = fmaxf(aw, 0.0f);
        ob.x = fmaxf(bx, 0.0f); ob.y = fmaxf(by, 0.0f);
        ob.z = fmaxf(bz, 0.0f); ob.w = fmaxf(bw, 0.0f);
        ((float4*)out)[(size_t)row0 * 16u + sub] = oa;
        ((float4*)out)[(size_t)row1 * 16u + sub] = ob;
    }
}

extern "C" void kernel_launch(void* const* d_in, const int* in_sizes, int n_in,
                              void* d_out, int out_size, void* d_ws, size_t ws_size,
                              hipStream_t stream) {
    const float* feat_values = (const float*)d_in[0];
    const float* W           = (const float*)d_in[1];
    const float* adj_values  = (const float*)d_in[2];
    const int*   feat_rows   = (const int*)d_in[3];
    const int*   feat_cols   = (const int*)d_in[4];
    const int*   adj_rows    = (const int*)d_in[5];
    const int*   adj_cols    = (const int*)d_in[6];
    float* out = (float*)d_out;

    // ---- workspace layout (bytes) ----
    char* ws = (char*)d_ws;
    int* bcur_x = (int*)(ws + 0);
    int* bcur_a = (int*)(ws + 2048);
    unsigned short* rs_a = (unsigned short*)(ws + 4096);
    float2* gx  = (float2*)(ws + 204800);
    float2* ga  = (float2*)(ws + 13817856);
    unsigned short* xw = (unsigned short*)(ws + 29833216);

    hipMemsetAsync(ws, 0, 4096, stream);    // bucket cursors

    // phase1: grid sized for the larger (A) side; X blocks past 625 early-exit
    dim3 gp1((N_EDGES + CHUNK - 1) / CHUNK, 2);
    phase1<<<gp1, 512, 0, stream>>>(feat_values, feat_rows, feat_cols,
                                    adj_values, adj_rows, adj_cols,
                                    bcur_x, bcur_a, gx, ga);
    sort_stage<<<2 * NB, 512, 0, stream>>>(bcur_x, gx, W, xw, bcur_a, ga, rs_a);
    spmm2<<<(N_NODES / 2 + 3) / 4, 256, 0, stream>>>(bcur_a, rs_a, ga, xw, out);
}